// Round 14
// baseline (669.561 us; speedup 1.0000x reference)
//
#include <hip/hip_runtime.h>
#include <hip/hip_cooperative_groups.h>
#include <math.h>

namespace cg = cooperative_groups;

#define NN 20000
#define NE 320000
#define NREL 9
#define NBASES 9
#define D_IN 128
#define D_HID 256
#define D_OUT 64
#define LN_EPS 1e-5f

#define N1 (NREL * D_HID + D_HID)   // 2560
#define N2 (NREL * D_OUT + D_OUT)   // 640
#define NBLK ((NN + 255) / 256)     // 79
#define FE_BLOCKS 1024              // cooperative front-end grid (4 blocks/CU)

typedef __attribute__((ext_vector_type(8))) short bf16x8;
typedef __attribute__((ext_vector_type(4))) float f32x4;

__device__ inline ushort f2b(float f) {
    unsigned u = __float_as_uint(f);
    return (ushort)((u + 0x7FFFu + ((u >> 16) & 1u)) >> 16);
}
__device__ inline float b2f(ushort h) { return __uint_as_float(((unsigned)h) << 16); }
__device__ inline unsigned pack2bf(float f0, float f1) {
    return (unsigned)f2b(f0) | ((unsigned)f2b(f1) << 16);
}

// ---------- cooperative front-end: zero+prep -> hist -> scan -> finalize -> scatter ----------
__global__ __launch_bounds__(256) void front_end(
    const float* __restrict__ bases1, const float* __restrict__ comp1, const float* __restrict__ root1,
    const float* __restrict__ bases2, const float* __restrict__ comp2, const float* __restrict__ root2,
    const float* __restrict__ x, const int* __restrict__ src, const int* __restrict__ dst,
    const int* __restrict__ etype,
    ushort* __restrict__ w1t, ushort* __restrict__ w2t, ushort* __restrict__ xbf,
    int* __restrict__ deg, int* __restrict__ local, int* __restrict__ bsum,
    int* __restrict__ offs, int* __restrict__ cursor, int* __restrict__ ep1)
{
    cg::grid_group grid = cg::this_grid();
    const int SZW1 = D_IN * D_HID;   // 32768
    const int SZW2 = D_HID * D_OUT;  // 16384
    const int SZX  = NN * D_IN;      // 2560000
    int tid = threadIdx.x;
    int gtid = blockIdx.x * 256 + tid;
    const int gstride = FE_BLOCKS * 256;

    // ---- P0: zero deg + basis-combined weights (coalesced) + x cast ----
    for (int i = gtid; i < NN; i += gstride) deg[i] = 0;
    for (int t = gtid; t < SZW1 + SZW2 + SZX; t += gstride) {
        if (t < SZW1) {
            int o = t & (D_HID - 1), k = t >> 8;
            float acc[NREL];
            #pragma unroll
            for (int r = 0; r < NREL; r++) acc[r] = 0.f;
            #pragma unroll
            for (int b = 0; b < NBASES; b++) {
                float bs = bases1[(b * D_IN + k) * D_HID + o];
                #pragma unroll
                for (int r = 0; r < NREL; r++) acc[r] += comp1[r * NBASES + b] * bs;
            }
            #pragma unroll
            for (int r = 0; r < NREL; r++)
                w1t[(r * D_HID + o) * D_IN + k] = f2b(acc[r]);
            w1t[(NREL * D_HID + o) * D_IN + k] = f2b(root1[k * D_HID + o]);
        } else if (t < SZW1 + SZW2) {
            int j = t - SZW1;
            int o = j & (D_OUT - 1), k = j >> 6;
            float acc[NREL];
            #pragma unroll
            for (int r = 0; r < NREL; r++) acc[r] = 0.f;
            #pragma unroll
            for (int b = 0; b < NBASES; b++) {
                float bs = bases2[(b * D_HID + k) * D_OUT + o];
                #pragma unroll
                for (int r = 0; r < NREL; r++) acc[r] += comp2[r * NBASES + b] * bs;
            }
            #pragma unroll
            for (int r = 0; r < NREL; r++)
                w2t[(r * D_OUT + o) * D_HID + k] = f2b(acc[r]);
            w2t[(NREL * D_OUT + o) * D_HID + k] = f2b(root2[k * D_OUT + o]);
        } else {
            int j = t - SZW1 - SZW2;
            xbf[j] = f2b(x[j]);
        }
    }
    grid.sync();

    // ---- P1: dst histogram ----
    for (int e = gtid; e < NE; e += gstride) atomicAdd(&deg[dst[e]], 1);
    grid.sync();

    // ---- P2: per-chunk local exclusive scan (first NBLK blocks) ----
    if (blockIdx.x < NBLK) {
        __shared__ int wsum[4];
        int lane = tid & 63, w = tid >> 6;
        int i = blockIdx.x * 256 + tid;
        int v = (i < NN) ? deg[i] : 0;
        int xs = v;
        #pragma unroll
        for (int d = 1; d < 64; d <<= 1) {
            int y = __shfl_up(xs, d, 64);
            if (lane >= d) xs += y;
        }
        if (lane == 63) wsum[w] = xs;
        __syncthreads();
        int woff = 0;
        for (int j = 0; j < w; j++) woff += wsum[j];
        if (i < NN) local[i] = woff + xs - v;
        if (tid == 255) bsum[blockIdx.x] = woff + xs;
    }
    grid.sync();

    // ---- P3: redundant top-scan + finalize offs/cursor ----
    if (blockIdx.x < NBLK) {
        __shared__ int boff_s[NBLK];
        if (tid < 64) {
            int carry = 0;
            for (int base = 0; base < NBLK; base += 64) {
                int i = base + tid;
                int v = (i < NBLK) ? bsum[i] : 0;
                int xs = v;
                #pragma unroll
                for (int d = 1; d < 64; d <<= 1) {
                    int y = __shfl_up(xs, d, 64);
                    if (tid >= d) xs += y;
                }
                if (i < NBLK) boff_s[i] = carry + xs - v;
                carry += __shfl(xs, 63, 64);
            }
        }
        __syncthreads();
        int i = blockIdx.x * 256 + tid;
        if (i < NN) {
            int o = local[i] + boff_s[i >> 8];
            offs[i] = o;
            cursor[i] = o;
        }
        if (i == NN) offs[NN] = NE;
    }
    grid.sync();

    // ---- P4: edge scatter (ep1 = src*N1 + rel*D_HID; ep2 == ep1>>2) ----
    for (int e = gtid; e < NE; e += gstride) {
        int d = dst[e];
        int s = src[e], r = etype[e];
        int pos = atomicAdd(&cursor[d], 1);
        ep1[pos] = s * N1 + r * D_HID;
    }
}

// ---------- bf16 MFMA GEMM (r10 config — best measured; structural plateau) ----------
__global__ __launch_bounds__(256) void gemm_bf16(
    const ushort* __restrict__ A, const ushort* __restrict__ Bt, ushort* __restrict__ C,
    int M, int N, int K)
{
    __shared__ ushort As[2][512 * 8];
    __shared__ ushort Bs[2][512 * 8];

    int tid = threadIdx.x;
    int lane = tid & 63, w = tid >> 6;
    int wm = w >> 1, wn = w & 1;
    int row0 = blockIdx.y * 128, col0 = blockIdx.x * 128;

    int r0 = tid >> 2, q0 = tid & 3;
    int mrw = r0 & 15, gw = r0 >> 4;
    int sw = q0 * 16 + ((mrw + 2 * q0) & 15);
    int lo0 = (gw * 64 + sw) * 8;
    int lo1 = ((gw + 4) * 64 + sw) * 8;
    int arow0 = min(row0 + r0, M - 1);
    int arow1 = min(row0 + r0 + 64, M - 1);
    const ushort* gA0 = &A[(size_t)arow0 * K + q0 * 8];
    const ushort* gA1 = &A[(size_t)arow1 * K + q0 * 8];
    const ushort* gB0 = &Bt[(size_t)(col0 + r0) * K + q0 * 8];
    const ushort* gB1 = &Bt[(size_t)(col0 + r0 + 64) * K + q0 * 8];

    int mr = lane & 15, kq = lane >> 4;
    int inner = (kq * 16 + ((mr + 2 * kq) & 15)) * 8;

    f32x4 acc[4][4];
    #pragma unroll
    for (int mt = 0; mt < 4; mt++)
        #pragma unroll
        for (int nt = 0; nt < 4; nt++)
            acc[mt][nt] = (f32x4){0.f, 0.f, 0.f, 0.f};

    {
        bf16x8 a0 = *(const bf16x8*)gA0;
        bf16x8 a1 = *(const bf16x8*)gA1;
        bf16x8 b0 = *(const bf16x8*)gB0;
        bf16x8 b1 = *(const bf16x8*)gB1;
        *(bf16x8*)&As[0][lo0] = a0;
        *(bf16x8*)&As[0][lo1] = a1;
        *(bf16x8*)&Bs[0][lo0] = b0;
        *(bf16x8*)&Bs[0][lo1] = b1;
    }

    const int NC = K >> 5;
    for (int c = 0; c < NC; c++) {
        __syncthreads();
        int cur = c & 1, nxt = cur ^ 1;
        bf16x8 a0, a1, b0, b1;
        bool more = (c + 1 < NC);
        if (more) {
            gA0 += 32; gA1 += 32; gB0 += 32; gB1 += 32;
            a0 = *(const bf16x8*)gA0;
            a1 = *(const bf16x8*)gA1;
            b0 = *(const bf16x8*)gB0;
            b1 = *(const bf16x8*)gB1;
        }

        bf16x8 af[4], bfr[4];
        #pragma unroll
        for (int mt = 0; mt < 4; mt++)
            af[mt] = *(const bf16x8*)&As[cur][(size_t)((wm * 4 + mt) * 64) * 8 + inner];
        #pragma unroll
        for (int nt = 0; nt < 4; nt++)
            bfr[nt] = *(const bf16x8*)&Bs[cur][(size_t)((wn * 4 + nt) * 64) * 8 + inner];
        #pragma unroll
        for (int mt = 0; mt < 4; mt++)
            #pragma unroll
            for (int nt = 0; nt < 4; nt++)
                acc[mt][nt] = __builtin_amdgcn_mfma_f32_16x16x32_bf16(
                    bfr[nt], af[mt], acc[mt][nt], 0, 0, 0);

        if (more) {
            *(bf16x8*)&As[nxt][lo0] = a0;
            *(bf16x8*)&As[nxt][lo1] = a1;
            *(bf16x8*)&Bs[nxt][lo0] = b0;
            *(bf16x8*)&Bs[nxt][lo1] = b1;
        }
    }

    int q = lane >> 4, cm = lane & 15;
    #pragma unroll
    for (int mt = 0; mt < 4; mt++) {
        int gr = row0 + wm * 64 + mt * 16 + cm;
        if (gr < M) {
            #pragma unroll
            for (int nt = 0; nt < 4; nt++) {
                int gc = col0 + wn * 64 + nt * 16 + q * 4;
                uint2 o;
                o.x = pack2bf(acc[mt][nt][0], acc[mt][nt][1]);
                o.y = pack2bf(acc[mt][nt][2], acc[mt][nt][3]);
                *(uint2*)&C[(size_t)gr * N + gc] = o;
            }
        }
    }
}

// ---------- gather1: 2 edges/wave (32-lane halves, 16 B/lane) -> max -> LN -> ReLU ----------
// Each half-wave loads a different edge's 256-channel message as bf16x8/lane.
// Cross-half shfl_xor(32) merges maxes; max is idempotent so the odd tail
// clamps both halves to the last edge. LN sums count each channel twice.
__global__ __launch_bounds__(256) void gather1(
    const ushort* __restrict__ xw1, const int* __restrict__ offs, const int* __restrict__ ep1,
    const float* __restrict__ bias, const float* __restrict__ g, const float* __restrict__ b,
    ushort* __restrict__ h)
{
    int n = blockIdx.x * 4 + (threadIdx.x >> 6);
    if (n >= NN) return;
    int lane = threadIdx.x & 63;
    int half = lane >> 5, sub = lane & 31;
    int ch8 = sub * 8;                       // this lane's 8-channel group
    int e0 = __builtin_amdgcn_readfirstlane(offs[n]);
    int e1 = __builtin_amdgcn_readfirstlane(offs[n + 1]);

    float mm[8];
    #pragma unroll
    for (int k = 0; k < 8; k++) mm[k] = -INFINITY;

    int e = e0;
    for (; e + 16 <= e1; e += 16) {
        int p[8];
        #pragma unroll
        for (int j = 0; j < 8; j++) p[j] = ep1[e + j * 2 + half];
        bf16x8 v[8];
        #pragma unroll
        for (int j = 0; j < 8; j++) v[j] = *(const bf16x8*)&xw1[(size_t)(p[j] + ch8)];
        #pragma unroll
        for (int j = 0; j < 8; j++)
            #pragma unroll
            for (int k = 0; k < 8; k++)
                mm[k] = fmaxf(mm[k], b2f((ushort)v[j][k]));
    }
    for (; e < e1; e += 2) {
        int ia = e + half;
        if (ia >= e1) ia = e1 - 1;           // duplicate last edge; max idempotent
        int p = ep1[ia];
        bf16x8 v = *(const bf16x8*)&xw1[(size_t)(p + ch8)];
        #pragma unroll
        for (int k = 0; k < 8; k++) mm[k] = fmaxf(mm[k], b2f((ushort)v[k]));
    }
    // merge halves
    #pragma unroll
    for (int k = 0; k < 8; k++) mm[k] = fmaxf(mm[k], __shfl_xor(mm[k], 32, 64));
    if (e1 == e0) {
        #pragma unroll
        for (int k = 0; k < 8; k++) mm[k] = 0.f;   // empty segment -> 0
    }

    bf16x8 rt = *(const bf16x8*)&xw1[(size_t)n * N1 + NREL * D_HID + ch8];
    float4 bia0 = *(const float4*)&bias[ch8];
    float4 bia1 = *(const float4*)&bias[ch8 + 4];
    float t[8];
    t[0] = mm[0] + b2f((ushort)rt[0]) + bia0.x;
    t[1] = mm[1] + b2f((ushort)rt[1]) + bia0.y;
    t[2] = mm[2] + b2f((ushort)rt[2]) + bia0.z;
    t[3] = mm[3] + b2f((ushort)rt[3]) + bia0.w;
    t[4] = mm[4] + b2f((ushort)rt[4]) + bia1.x;
    t[5] = mm[5] + b2f((ushort)rt[5]) + bia1.y;
    t[6] = mm[6] + b2f((ushort)rt[6]) + bia1.z;
    t[7] = mm[7] + b2f((ushort)rt[7]) + bia1.w;

    float s = 0.f, s2 = 0.f;
    #pragma unroll
    for (int k = 0; k < 8; k++) { s += t[k]; s2 += t[k] * t[k]; }
    #pragma unroll
    for (int m = 32; m >= 1; m >>= 1) {
        s  += __shfl_xor(s,  m, 64);
        s2 += __shfl_xor(s2, m, 64);
    }
    // both halves contribute -> each channel counted twice
    float mu = s * (1.f / (2 * D_HID));
    float var = s2 * (1.f / (2 * D_HID)) - mu * mu;
    float rs = rsqrtf(var + LN_EPS);

    if (half == 0) {
        float4 g0 = *(const float4*)&g[ch8], g1v = *(const float4*)&g[ch8 + 4];
        float4 b0 = *(const float4*)&b[ch8], b1v = *(const float4*)&b[ch8 + 4];
        float gg[8] = {g0.x, g0.y, g0.z, g0.w, g1v.x, g1v.y, g1v.z, g1v.w};
        float bb[8] = {b0.x, b0.y, b0.z, b0.w, b1v.x, b1v.y, b1v.z, b1v.w};
        bf16x8 o;
        #pragma unroll
        for (int k = 0; k < 8; k++)
            o[k] = (short)f2b(fmaxf((t[k] - mu) * rs * gg[k] + bb[k], 0.f));
        *(bf16x8*)&h[(size_t)n * D_HID + ch8] = o;
    }
}

// ---------- gather2: sum over in-edges + root + bias -> LN -> log_softmax -> out ----------
__global__ __launch_bounds__(256) void gather2(
    const ushort* __restrict__ xw2, const int* __restrict__ offs, const int* __restrict__ ep1,
    const float* __restrict__ bias, const float* __restrict__ g, const float* __restrict__ b,
    float* __restrict__ out)
{
    int n = blockIdx.x * 4 + (threadIdx.x >> 6);
    if (n >= NN) return;
    int lane = threadIdx.x & 63;
    int e0 = __builtin_amdgcn_readfirstlane(offs[n]);
    int e1 = __builtin_amdgcn_readfirstlane(offs[n + 1]);

    float s = 0.f;
    int e = e0;
    for (; e + 8 <= e1; e += 8) {
        int p[8];
        #pragma unroll
        for (int j = 0; j < 8; j++) p[j] = ep1[e + j] >> 2;
        float a[8];
        #pragma unroll
        for (int j = 0; j < 8; j++) a[j] = b2f(xw2[(size_t)(p[j] + lane)]);
        s += ((a[0] + a[1]) + (a[2] + a[3])) + ((a[4] + a[5]) + (a[6] + a[7]));
    }
    for (; e < e1; e++) {
        s += b2f(xw2[(size_t)((ep1[e] >> 2) + lane)]);
    }
    float v = s + b2f(xw2[(size_t)n * N2 + NREL * D_OUT + lane]) + bias[lane];

    float sm = v, s2 = v * v;
    #pragma unroll
    for (int m = 32; m >= 1; m >>= 1) {
        sm += __shfl_xor(sm, m, 64);
        s2 += __shfl_xor(s2, m, 64);
    }
    float mu = sm * (1.f / D_OUT);
    float var = s2 * (1.f / D_OUT) - mu * mu;
    float y = (v - mu) * rsqrtf(var + LN_EPS) * g[lane] + b[lane];

    float mx = y;
    #pragma unroll
    for (int m = 32; m >= 1; m >>= 1) mx = fmaxf(mx, __shfl_xor(mx, m, 64));
    float ex = __expf(y - mx);
    float se = ex;
    #pragma unroll
    for (int m = 32; m >= 1; m >>= 1) se += __shfl_xor(se, m, 64);
    out[(size_t)n * D_OUT + lane] = y - mx - logf(se);
}

extern "C" void kernel_launch(void* const* d_in, const int* in_sizes, int n_in,
                              void* d_out, int out_size, void* d_ws, size_t ws_size,
                              hipStream_t stream)
{
    const float* x      = (const float*)d_in[0];
    const int*   eidx   = (const int*)  d_in[1];
    const int*   etype  = (const int*)  d_in[2];
    const float* bases1 = (const float*)d_in[3];
    const float* comp1  = (const float*)d_in[4];
    const float* root1  = (const float*)d_in[5];
    const float* bias1  = (const float*)d_in[6];
    const float* g1     = (const float*)d_in[7];
    const float* b1     = (const float*)d_in[8];
    const float* bases2 = (const float*)d_in[9];
    const float* comp2  = (const float*)d_in[10];
    const float* root2  = (const float*)d_in[11];
    const float* bias2  = (const float*)d_in[12];
    const float* g2     = (const float*)d_in[13];
    const float* b2     = (const float*)d_in[14];

    const int* src = eidx;
    const int* dst = eidx + NE;

    char* p = (char*)d_ws;
    auto alloc = [&](size_t bytes) -> char* {
        char* r = p;
        p += (bytes + 255) & ~(size_t)255;
        return r;
    };
    ushort* xbf    = (ushort*)alloc((size_t)NN * D_IN * 2);
    ushort* w1t    = (ushort*)alloc((size_t)N1 * D_IN * 2);
    ushort* w2t    = (ushort*)alloc((size_t)N2 * D_HID * 2);
    ushort* xw1    = (ushort*)alloc((size_t)NN * N1 * 2);
    ushort* xw2    = (ushort*)alloc((size_t)NN * N2 * 2);
    ushort* h      = (ushort*)alloc((size_t)NN * D_HID * 2);
    int*    deg    = (int*)   alloc((size_t)NN * 4);
    int*    local  = (int*)   alloc((size_t)NN * 4);
    int*    bsum   = (int*)   alloc((size_t)NBLK * 4);
    int*    offs   = (int*)   alloc((size_t)(NN + 1) * 4);
    int*    cursor = (int*)   alloc((size_t)NN * 4);
    int*    ep1    = (int*)   alloc((size_t)NE * 4);

    // single cooperative front-end dispatch (replaces memset + 5 kernels)
    void* args[] = {
        (void*)&bases1, (void*)&comp1, (void*)&root1,
        (void*)&bases2, (void*)&comp2, (void*)&root2,
        (void*)&x, (void*)&src, (void*)&dst, (void*)&etype,
        (void*)&w1t, (void*)&w2t, (void*)&xbf,
        (void*)&deg, (void*)&local, (void*)&bsum,
        (void*)&offs, (void*)&cursor, (void*)&ep1
    };
    hipLaunchCooperativeKernel((void*)front_end, dim3(FE_BLOCKS), dim3(256),
                               args, 0, stream);

    gemm_bf16<<<dim3(N1 / 128, (NN + 127) / 128), 256, 0, stream>>>(xbf, w1t, xw1, NN, N1, D_IN);
    gather1<<<(NN + 3) / 4, 256, 0, stream>>>(xw1, offs, ep1, bias1, g1, b1, h);

    gemm_bf16<<<dim3(N2 / 128, (NN + 127) / 128), 256, 0, stream>>>(h, w2t, xw2, NN, N2, D_HID);
    gather2<<<(NN + 3) / 4, 256, 0, stream>>>(xw2, offs, ep1, bias2, g2, b2, (float*)d_out);
}

// Round 15
// 241.539 us; speedup vs baseline: 2.7721x; 2.7721x over previous
//
#include <hip/hip_runtime.h>
#include <math.h>

#define NN 20000
#define NE 320000
#define NREL 9
#define NBASES 9
#define D_IN 128
#define D_HID 256
#define D_OUT 64
#define LN_EPS 1e-5f

#define N1 (NREL * D_HID + D_HID)   // 2560
#define N2 (NREL * D_OUT + D_OUT)   // 640
#define NBLK ((NN + 255) / 256)     // 79

typedef __attribute__((ext_vector_type(8))) short bf16x8;
typedef __attribute__((ext_vector_type(4))) float f32x4;

__device__ inline ushort f2b(float f) {
    unsigned u = __float_as_uint(f);
    return (ushort)((u + 0x7FFFu + ((u >> 16) & 1u)) >> 16);
}
__device__ inline float b2f(ushort h) { return __uint_as_float(((unsigned)h) << 16); }
__device__ inline unsigned pack2bf(float f0, float f1) {
    return (unsigned)f2b(f0) | ((unsigned)f2b(f1) << 16);
}

// ---------- fused prep: weights (coalesced basis reads) + x cast + dst histogram ----------
__global__ __launch_bounds__(256) void prep_all(
    const float* __restrict__ bases1, const float* __restrict__ comp1, const float* __restrict__ root1,
    const float* __restrict__ bases2, const float* __restrict__ comp2, const float* __restrict__ root2,
    const float* __restrict__ x, const int* __restrict__ dst,
    ushort* __restrict__ w1t, ushort* __restrict__ w2t, ushort* __restrict__ xbf,
    int* __restrict__ deg)
{
    const int SZW1 = D_IN * D_HID;   // 32768
    const int SZW2 = D_HID * D_OUT;  // 16384
    const int SZX  = NN * D_IN;      // 2560000
    int tid = blockIdx.x * 256 + threadIdx.x;
    if (tid < SZW1) {
        int o = tid & (D_HID - 1), k = tid >> 8;
        float acc[NREL];
        #pragma unroll
        for (int r = 0; r < NREL; r++) acc[r] = 0.f;
        #pragma unroll
        for (int b = 0; b < NBASES; b++) {
            float bs = bases1[(b * D_IN + k) * D_HID + o];
            #pragma unroll
            for (int r = 0; r < NREL; r++) acc[r] += comp1[r * NBASES + b] * bs;
        }
        #pragma unroll
        for (int r = 0; r < NREL; r++)
            w1t[(r * D_HID + o) * D_IN + k] = f2b(acc[r]);
        w1t[(NREL * D_HID + o) * D_IN + k] = f2b(root1[k * D_HID + o]);
    } else if (tid < SZW1 + SZW2) {
        int j = tid - SZW1;
        int o = j & (D_OUT - 1), k = j >> 6;
        float acc[NREL];
        #pragma unroll
        for (int r = 0; r < NREL; r++) acc[r] = 0.f;
        #pragma unroll
        for (int b = 0; b < NBASES; b++) {
            float bs = bases2[(b * D_HID + k) * D_OUT + o];
            #pragma unroll
            for (int r = 0; r < NREL; r++) acc[r] += comp2[r * NBASES + b] * bs;
        }
        #pragma unroll
        for (int r = 0; r < NREL; r++)
            w2t[(r * D_OUT + o) * D_HID + k] = f2b(acc[r]);
        w2t[(NREL * D_OUT + o) * D_HID + k] = f2b(root2[k * D_OUT + o]);
    } else if (tid < SZW1 + SZW2 + SZX) {
        int j = tid - SZW1 - SZW2;
        xbf[j] = f2b(x[j]);
    } else if (tid < SZW1 + SZW2 + SZX + NE) {
        int e = tid - SZW1 - SZW2 - SZX;
        atomicAdd(&deg[dst[e]], 1);
    }
}

// ---------- CSR build ----------
__global__ __launch_bounds__(256) void scan_blk(
    const int* __restrict__ deg, int* __restrict__ local, int* __restrict__ bsum)
{
    __shared__ int wsum[4];
    int tid = threadIdx.x, lane = tid & 63, w = tid >> 6;
    int i = blockIdx.x * 256 + tid;
    int v = (i < NN) ? deg[i] : 0;
    int x = v;
    #pragma unroll
    for (int d = 1; d < 64; d <<= 1) {
        int y = __shfl_up(x, d, 64);
        if (lane >= d) x += y;
    }
    if (lane == 63) wsum[w] = x;
    __syncthreads();
    int woff = 0;
    for (int j = 0; j < w; j++) woff += wsum[j];
    if (i < NN) local[i] = woff + x - v;
    if (tid == 255) bsum[blockIdx.x] = woff + x;
}

__global__ __launch_bounds__(256) void scan_fin(
    const int* __restrict__ local, const int* __restrict__ bsum,
    int* __restrict__ offs, int* __restrict__ cursor)
{
    __shared__ int boff_s[NBLK];
    int tid = threadIdx.x;
    if (tid < 64) {
        int carry = 0;
        for (int base = 0; base < NBLK; base += 64) {
            int i = base + tid;
            int v = (i < NBLK) ? bsum[i] : 0;
            int x = v;
            #pragma unroll
            for (int d = 1; d < 64; d <<= 1) {
                int y = __shfl_up(x, d, 64);
                if (tid >= d) x += y;
            }
            if (i < NBLK) boff_s[i] = carry + x - v;
            carry += __shfl(x, 63, 64);
        }
    }
    __syncthreads();
    int i = blockIdx.x * 256 + tid;
    if (i < NN) {
        int o = local[i] + boff_s[i >> 8];
        offs[i] = o;
        cursor[i] = o;
    }
    if (i == NN) offs[NN] = NE;
}

__global__ __launch_bounds__(256) void scatter_ep(
    const int* __restrict__ src, const int* __restrict__ dst, const int* __restrict__ etype,
    int* __restrict__ cursor, int* __restrict__ ep1)
{
    int e = blockIdx.x * 256 + threadIdx.x;
    if (e >= NE) return;
    int d = dst[e];
    int s = src[e], r = etype[e];
    int pos = atomicAdd(&cursor[d], 1);
    ep1[pos] = s * N1 + r * D_HID;
}

// ---------- bf16 MFMA GEMM (r10 config — best measured; structural plateau) ----------
__global__ __launch_bounds__(256) void gemm_bf16(
    const ushort* __restrict__ A, const ushort* __restrict__ Bt, ushort* __restrict__ C,
    int M, int N, int K)
{
    __shared__ ushort As[2][512 * 8];
    __shared__ ushort Bs[2][512 * 8];

    int tid = threadIdx.x;
    int lane = tid & 63, w = tid >> 6;
    int wm = w >> 1, wn = w & 1;
    int row0 = blockIdx.y * 128, col0 = blockIdx.x * 128;

    int r0 = tid >> 2, q0 = tid & 3;
    int mrw = r0 & 15, gw = r0 >> 4;
    int sw = q0 * 16 + ((mrw + 2 * q0) & 15);
    int lo0 = (gw * 64 + sw) * 8;
    int lo1 = ((gw + 4) * 64 + sw) * 8;
    int arow0 = min(row0 + r0, M - 1);
    int arow1 = min(row0 + r0 + 64, M - 1);
    const ushort* gA0 = &A[(size_t)arow0 * K + q0 * 8];
    const ushort* gA1 = &A[(size_t)arow1 * K + q0 * 8];
    const ushort* gB0 = &Bt[(size_t)(col0 + r0) * K + q0 * 8];
    const ushort* gB1 = &Bt[(size_t)(col0 + r0 + 64) * K + q0 * 8];

    int mr = lane & 15, kq = lane >> 4;
    int inner = (kq * 16 + ((mr + 2 * kq) & 15)) * 8;

    f32x4 acc[4][4];
    #pragma unroll
    for (int mt = 0; mt < 4; mt++)
        #pragma unroll
        for (int nt = 0; nt < 4; nt++)
            acc[mt][nt] = (f32x4){0.f, 0.f, 0.f, 0.f};

    {
        bf16x8 a0 = *(const bf16x8*)gA0;
        bf16x8 a1 = *(const bf16x8*)gA1;
        bf16x8 b0 = *(const bf16x8*)gB0;
        bf16x8 b1 = *(const bf16x8*)gB1;
        *(bf16x8*)&As[0][lo0] = a0;
        *(bf16x8*)&As[0][lo1] = a1;
        *(bf16x8*)&Bs[0][lo0] = b0;
        *(bf16x8*)&Bs[0][lo1] = b1;
    }

    const int NC = K >> 5;
    for (int c = 0; c < NC; c++) {
        __syncthreads();
        int cur = c & 1, nxt = cur ^ 1;
        bf16x8 a0, a1, b0, b1;
        bool more = (c + 1 < NC);
        if (more) {
            gA0 += 32; gA1 += 32; gB0 += 32; gB1 += 32;
            a0 = *(const bf16x8*)gA0;
            a1 = *(const bf16x8*)gA1;
            b0 = *(const bf16x8*)gB0;
            b1 = *(const bf16x8*)gB1;
        }

        bf16x8 af[4], bfr[4];
        #pragma unroll
        for (int mt = 0; mt < 4; mt++)
            af[mt] = *(const bf16x8*)&As[cur][(size_t)((wm * 4 + mt) * 64) * 8 + inner];
        #pragma unroll
        for (int nt = 0; nt < 4; nt++)
            bfr[nt] = *(const bf16x8*)&Bs[cur][(size_t)((wn * 4 + nt) * 64) * 8 + inner];
        #pragma unroll
        for (int mt = 0; mt < 4; mt++)
            #pragma unroll
            for (int nt = 0; nt < 4; nt++)
                acc[mt][nt] = __builtin_amdgcn_mfma_f32_16x16x32_bf16(
                    bfr[nt], af[mt], acc[mt][nt], 0, 0, 0);

        if (more) {
            *(bf16x8*)&As[nxt][lo0] = a0;
            *(bf16x8*)&As[nxt][lo1] = a1;
            *(bf16x8*)&Bs[nxt][lo0] = b0;
            *(bf16x8*)&Bs[nxt][lo1] = b1;
        }
    }

    int q = lane >> 4, cm = lane & 15;
    #pragma unroll
    for (int mt = 0; mt < 4; mt++) {
        int gr = row0 + wm * 64 + mt * 16 + cm;
        if (gr < M) {
            #pragma unroll
            for (int nt = 0; nt < 4; nt++) {
                int gc = col0 + wn * 64 + nt * 16 + q * 4;
                uint2 o;
                o.x = pack2bf(acc[mt][nt][0], acc[mt][nt][1]);
                o.y = pack2bf(acc[mt][nt][2], acc[mt][nt][3]);
                *(uint2*)&C[(size_t)gr * N + gc] = o;
            }
        }
    }
}

// ---------- gather1: 2 edges/wave (32-lane halves, 16 B/lane) -> max -> LN -> ReLU ----------
__global__ __launch_bounds__(256) void gather1(
    const ushort* __restrict__ xw1, const int* __restrict__ offs, const int* __restrict__ ep1,
    const float* __restrict__ bias, const float* __restrict__ g, const float* __restrict__ b,
    ushort* __restrict__ h)
{
    int n = blockIdx.x * 4 + (threadIdx.x >> 6);
    if (n >= NN) return;
    int lane = threadIdx.x & 63;
    int half = lane >> 5, sub = lane & 31;
    int ch8 = sub * 8;                       // this lane's 8-channel group
    int e0 = __builtin_amdgcn_readfirstlane(offs[n]);
    int e1 = __builtin_amdgcn_readfirstlane(offs[n + 1]);

    float mm[8];
    #pragma unroll
    for (int k = 0; k < 8; k++) mm[k] = -INFINITY;

    int e = e0;
    for (; e + 16 <= e1; e += 16) {
        int p[8];
        #pragma unroll
        for (int j = 0; j < 8; j++) p[j] = ep1[e + j * 2 + half];
        bf16x8 v[8];
        #pragma unroll
        for (int j = 0; j < 8; j++) v[j] = *(const bf16x8*)&xw1[(size_t)(p[j] + ch8)];
        #pragma unroll
        for (int j = 0; j < 8; j++)
            #pragma unroll
            for (int k = 0; k < 8; k++)
                mm[k] = fmaxf(mm[k], b2f((ushort)v[j][k]));
    }
    for (; e < e1; e += 2) {
        int ia = e + half;
        if (ia >= e1) ia = e1 - 1;           // duplicate last edge; max idempotent
        int p = ep1[ia];
        bf16x8 v = *(const bf16x8*)&xw1[(size_t)(p + ch8)];
        #pragma unroll
        for (int k = 0; k < 8; k++) mm[k] = fmaxf(mm[k], b2f((ushort)v[k]));
    }
    #pragma unroll
    for (int k = 0; k < 8; k++) mm[k] = fmaxf(mm[k], __shfl_xor(mm[k], 32, 64));
    if (e1 == e0) {
        #pragma unroll
        for (int k = 0; k < 8; k++) mm[k] = 0.f;   // empty segment -> 0
    }

    bf16x8 rt = *(const bf16x8*)&xw1[(size_t)n * N1 + NREL * D_HID + ch8];
    float4 bia0 = *(const float4*)&bias[ch8];
    float4 bia1 = *(const float4*)&bias[ch8 + 4];
    float t[8];
    t[0] = mm[0] + b2f((ushort)rt[0]) + bia0.x;
    t[1] = mm[1] + b2f((ushort)rt[1]) + bia0.y;
    t[2] = mm[2] + b2f((ushort)rt[2]) + bia0.z;
    t[3] = mm[3] + b2f((ushort)rt[3]) + bia0.w;
    t[4] = mm[4] + b2f((ushort)rt[4]) + bia1.x;
    t[5] = mm[5] + b2f((ushort)rt[5]) + bia1.y;
    t[6] = mm[6] + b2f((ushort)rt[6]) + bia1.z;
    t[7] = mm[7] + b2f((ushort)rt[7]) + bia1.w;

    float s = 0.f, s2 = 0.f;
    #pragma unroll
    for (int k = 0; k < 8; k++) { s += t[k]; s2 += t[k] * t[k]; }
    #pragma unroll
    for (int m = 32; m >= 1; m >>= 1) {
        s  += __shfl_xor(s,  m, 64);
        s2 += __shfl_xor(s2, m, 64);
    }
    // both halves contribute -> each channel counted twice
    float mu = s * (1.f / (2 * D_HID));
    float var = s2 * (1.f / (2 * D_HID)) - mu * mu;
    float rs = rsqrtf(var + LN_EPS);

    if (half == 0) {
        float4 g0 = *(const float4*)&g[ch8], g1v = *(const float4*)&g[ch8 + 4];
        float4 b0 = *(const float4*)&b[ch8], b1v = *(const float4*)&b[ch8 + 4];
        float gg[8] = {g0.x, g0.y, g0.z, g0.w, g1v.x, g1v.y, g1v.z, g1v.w};
        float bb[8] = {b0.x, b0.y, b0.z, b0.w, b1v.x, b1v.y, b1v.z, b1v.w};
        bf16x8 o;
        #pragma unroll
        for (int k = 0; k < 8; k++)
            o[k] = (short)f2b(fmaxf((t[k] - mu) * rs * gg[k] + bb[k], 0.f));
        *(bf16x8*)&h[(size_t)n * D_HID + ch8] = o;
    }
}

// ---------- gather2: sum over in-edges + root + bias -> LN -> log_softmax -> out ----------
__global__ __launch_bounds__(256) void gather2(
    const ushort* __restrict__ xw2, const int* __restrict__ offs, const int* __restrict__ ep1,
    const float* __restrict__ bias, const float* __restrict__ g, const float* __restrict__ b,
    float* __restrict__ out)
{
    int n = blockIdx.x * 4 + (threadIdx.x >> 6);
    if (n >= NN) return;
    int lane = threadIdx.x & 63;
    int e0 = __builtin_amdgcn_readfirstlane(offs[n]);
    int e1 = __builtin_amdgcn_readfirstlane(offs[n + 1]);

    float s = 0.f;
    int e = e0;
    for (; e + 8 <= e1; e += 8) {
        int p[8];
        #pragma unroll
        for (int j = 0; j < 8; j++) p[j] = ep1[e + j] >> 2;
        float a[8];
        #pragma unroll
        for (int j = 0; j < 8; j++) a[j] = b2f(xw2[(size_t)(p[j] + lane)]);
        s += ((a[0] + a[1]) + (a[2] + a[3])) + ((a[4] + a[5]) + (a[6] + a[7]));
    }
    for (; e < e1; e++) {
        s += b2f(xw2[(size_t)((ep1[e] >> 2) + lane)]);
    }
    float v = s + b2f(xw2[(size_t)n * N2 + NREL * D_OUT + lane]) + bias[lane];

    float sm = v, s2 = v * v;
    #pragma unroll
    for (int m = 32; m >= 1; m >>= 1) {
        sm += __shfl_xor(sm, m, 64);
        s2 += __shfl_xor(s2, m, 64);
    }
    float mu = sm * (1.f / D_OUT);
    float var = s2 * (1.f / D_OUT) - mu * mu;
    float y = (v - mu) * rsqrtf(var + LN_EPS) * g[lane] + b[lane];

    float mx = y;
    #pragma unroll
    for (int m = 32; m >= 1; m >>= 1) mx = fmaxf(mx, __shfl_xor(mx, m, 64));
    float ex = __expf(y - mx);
    float se = ex;
    #pragma unroll
    for (int m = 32; m >= 1; m >>= 1) se += __shfl_xor(se, m, 64);
    out[(size_t)n * D_OUT + lane] = y - mx - logf(se);
}

extern "C" void kernel_launch(void* const* d_in, const int* in_sizes, int n_in,
                              void* d_out, int out_size, void* d_ws, size_t ws_size,
                              hipStream_t stream)
{
    const float* x      = (const float*)d_in[0];
    const int*   eidx   = (const int*)  d_in[1];
    const int*   etype  = (const int*)  d_in[2];
    const float* bases1 = (const float*)d_in[3];
    const float* comp1  = (const float*)d_in[4];
    const float* root1  = (const float*)d_in[5];
    const float* bias1  = (const float*)d_in[6];
    const float* g1     = (const float*)d_in[7];
    const float* b1     = (const float*)d_in[8];
    const float* bases2 = (const float*)d_in[9];
    const float* comp2  = (const float*)d_in[10];
    const float* root2  = (const float*)d_in[11];
    const float* bias2  = (const float*)d_in[12];
    const float* g2     = (const float*)d_in[13];
    const float* b2     = (const float*)d_in[14];

    const int* src = eidx;
    const int* dst = eidx + NE;

    char* p = (char*)d_ws;
    auto alloc = [&](size_t bytes) -> char* {
        char* r = p;
        p += (bytes + 255) & ~(size_t)255;
        return r;
    };
    ushort* xbf    = (ushort*)alloc((size_t)NN * D_IN * 2);
    ushort* w1t    = (ushort*)alloc((size_t)N1 * D_IN * 2);
    ushort* w2t    = (ushort*)alloc((size_t)N2 * D_HID * 2);
    ushort* xw1    = (ushort*)alloc((size_t)NN * N1 * 2);
    ushort* xw2    = (ushort*)alloc((size_t)NN * N2 * 2);
    ushort* h      = (ushort*)alloc((size_t)NN * D_HID * 2);
    int*    deg    = (int*)   alloc((size_t)NN * 4);
    int*    local  = (int*)   alloc((size_t)NN * 4);
    int*    bsum   = (int*)   alloc((size_t)NBLK * 4);
    int*    offs   = (int*)   alloc((size_t)(NN + 1) * 4);
    int*    cursor = (int*)   alloc((size_t)NN * 4);
    int*    ep1    = (int*)   alloc((size_t)NE * 4);

    hipMemsetAsync(deg, 0, (size_t)NN * 4, stream);
    const int SZP = D_IN * D_HID + D_HID * D_OUT + NN * D_IN + NE;
    prep_all<<<(SZP + 255) / 256, 256, 0, stream>>>(
        bases1, comp1, root1, bases2, comp2, root2, x, dst, w1t, w2t, xbf, deg);

    scan_blk<<<NBLK, 256, 0, stream>>>(deg, local, bsum);
    scan_fin<<<NBLK, 256, 0, stream>>>(local, bsum, offs, cursor);
    scatter_ep<<<(NE + 255) / 256, 256, 0, stream>>>(src, dst, etype, cursor, ep1);

    gemm_bf16<<<dim3(N1 / 128, (NN + 127) / 128), 256, 0, stream>>>(xbf, w1t, xw1, NN, N1, D_IN);
    gather1<<<(NN + 3) / 4, 256, 0, stream>>>(xw1, offs, ep1, bias1, g1, b1, h);

    gemm_bf16<<<dim3(N2 / 128, (NN + 127) / 128), 256, 0, stream>>>(h, w2t, xw2, NN, N2, D_HID);
    gather2<<<(NN + 3) / 4, 256, 0, stream>>>(xw2, offs, ep1, bias2, g2, b2, (float*)d_out);
}